// Round 7
// baseline (918.452 us; speedup 1.0000x reference)
//
#include <hip/hip_runtime.h>
#include <hip/hip_bf16.h>
#include <hip/hip_fp16.h>

// GCN 2-layer inference, N=100000, E=1600000, F_IN=100, H=128, C=47.
// R7: single fused CSR-build kernel (count -> scan -> scatter) using a
// software grid barrier (device-scope atomic + threadfence; 782 blocks is
// well under co-residency capacity). Edge src/dst/slot live in REGISTERS
// across phases: ei read once, epos array eliminated. scan_one (302us
// single-block disaster) gone. agg1 reverted to R3 form: dinv folded into
// gemm1 output scaling, agg is a pure sum. gemm2 before agg2 (96B gathers).

constexpr int N    = 100000;
constexpr int E    = 1600000;
constexpr int FIN  = 100;
constexpr int HD   = 128;
constexpr int C    = 47;
constexpr int C48  = 48;
constexpr int EN   = E + N;            // edges + self loops
constexpr int EPT  = 8;                // edges per thread in build
constexpr int NB_BUILD = (E / EPT + 255) / 256;          // 782 blocks
constexpr int SCAN_BLOCKS = (N + 255) / 256;             // 391 (< NB_BUILD)

// ---------- grid barrier (spin on device-scope atomic) ----------

__device__ __forceinline__ void grid_bar(int* bar, int target) {
    __syncthreads();
    if (threadIdx.x == 0) {
        __threadfence();   // release: flush this CU/XCD's prior writes
        __hip_atomic_fetch_add(bar, 1, __ATOMIC_RELEASE, __HIP_MEMORY_SCOPE_AGENT);
        while (__hip_atomic_load(bar, __ATOMIC_ACQUIRE, __HIP_MEMORY_SCOPE_AGENT) < target)
            __builtin_amdgcn_s_sleep(2);
        __threadfence();   // acquire: invalidate stale lines
    }
    __syncthreads();
}

// ---------- fused CSR build ----------
// A: count degrees (slot kept in regs)  B: block partial sums of deg
// C: block 0 scans 391 partials         D: rowptr/dinv/self-loop writes
// E: scatter edges from regs

__global__ __launch_bounds__(256) void build_csr(const int* __restrict__ ei,
                                                 int* __restrict__ cnt,
                                                 int* __restrict__ rowptr,
                                                 float* __restrict__ dinv,
                                                 int* __restrict__ ep,
                                                 int* __restrict__ partials,
                                                 int* __restrict__ bar) {
    const int tid = threadIdx.x;
    const int T = blockIdx.x * 256 + tid;
    __shared__ int sm[256];

    // ---- phase A: count + record slot in registers ----
    int es[EPT], ed[EPT], pp[EPT];
    const int e0 = T * EPT;
#pragma unroll
    for (int k = 0; k < EPT; ++k) {
        int e = e0 + k;
        if (e < E) {
            es[k] = __builtin_nontemporal_load(&ei[e]);
            ed[k] = __builtin_nontemporal_load(&ei[E + e]);
            pp[k] = atomicAdd(&cnt[ed[k]], 1);
        }
    }
    grid_bar(bar, NB_BUILD);

    // ---- phase B: per-block inclusive scan of degrees ----
    int node = blockIdx.x * 256 + tid;   // valid for blocks < SCAN_BLOCKS
    int deg = 0, excl_local = 0;
    if (blockIdx.x < SCAN_BLOCKS) {
        deg = (node < N) ? cnt[node] + 1 : 0;    // +1 self loop
        sm[tid] = deg;
        __syncthreads();
        for (int off = 1; off < 256; off <<= 1) {
            int v = (tid >= off) ? sm[tid - off] : 0;
            __syncthreads();
            sm[tid] += v;
            __syncthreads();
        }
        excl_local = sm[tid] - deg;
        if (tid == 255) partials[blockIdx.x] = sm[255];
    }
    grid_bar(bar, 2 * NB_BUILD);

    // ---- phase C: block 0 exclusive-scans the 391 partials ----
    if (blockIdx.x == 0) {
        int a = (2 * tid     < SCAN_BLOCKS) ? partials[2 * tid]     : 0;
        int b = (2 * tid + 1 < SCAN_BLOCKS) ? partials[2 * tid + 1] : 0;
        int ps = a + b;
        sm[tid] = ps;
        __syncthreads();
        for (int off = 1; off < 256; off <<= 1) {
            int v = (tid >= off) ? sm[tid - off] : 0;
            __syncthreads();
            sm[tid] += v;
            __syncthreads();
        }
        int pexcl = sm[tid] - ps;
        if (2 * tid     < SCAN_BLOCKS) partials[2 * tid]     = pexcl;
        if (2 * tid + 1 < SCAN_BLOCKS) partials[2 * tid + 1] = pexcl + a;
    }
    grid_bar(bar, 3 * NB_BUILD);

    // ---- phase D: write rowptr, dinv, self-loop slots ----
    if (blockIdx.x < SCAN_BLOCKS) {
        int rp = partials[blockIdx.x] + excl_local;
        if (node < N) {
            rowptr[node] = rp;
            dinv[node] = rsqrtf((float)deg);
            ep[rp] = node;               // self loop at slot 0
        }
        if (node == N) rowptr[N] = EN;
    }
    grid_bar(bar, 4 * NB_BUILD);

    // ---- phase E: scatter edges from registers ----
#pragma unroll
    for (int k = 0; k < EPT; ++k) {
        int e = e0 + k;
        if (e < E)
            __builtin_nontemporal_store(es[k], &ep[rowptr[ed[k]] + 1 + pp[k]]);
    }
}

// ---------- GEMM1: xw[N,128] (fp16) = dinv[n] * (x[N,100] @ W1) ----------

__global__ __launch_bounds__(256) void gemm1(const float* __restrict__ x,
                                             const float* __restrict__ W1,
                                             const float* __restrict__ dinv,
                                             __half* __restrict__ xwh) {
    __shared__ float sW[FIN * HD];     // 51.2 KB
    __shared__ float sX[64 * FIN];     // 25.6 KB
    int tx = threadIdx.x;
    size_t node0 = (size_t)blockIdx.x * 64;

    const float4* W4 = (const float4*)W1;
    for (int i = tx; i < FIN * HD / 4; i += 256) ((float4*)sW)[i] = W4[i];
    size_t base4 = node0 * FIN / 4;          // node0*100 divisible by 4
    const float4* x4 = (const float4*)x;
    for (int i = tx; i < 64 * FIN / 4; i += 256) {
        size_t g = base4 + i;
        ((float4*)sX)[i] = (g < (size_t)N * FIN / 4) ? x4[g]
                                                     : make_float4(0.f, 0.f, 0.f, 0.f);
    }
    __syncthreads();

    int col = (tx & 31) * 4;        // 0..124
    int nb  = (tx >> 5) * 8;        // 0..56
    float4 acc[8];
#pragma unroll
    for (int i = 0; i < 8; ++i) acc[i] = make_float4(0.f, 0.f, 0.f, 0.f);

    for (int k = 0; k < FIN; ++k) {
        float4 b = *(const float4*)&sW[k * HD + col];
#pragma unroll
        for (int i = 0; i < 8; ++i) {
            float a = sX[(nb + i) * FIN + k];
            acc[i].x = fmaf(a, b.x, acc[i].x);
            acc[i].y = fmaf(a, b.y, acc[i].y);
            acc[i].z = fmaf(a, b.z, acc[i].z);
            acc[i].w = fmaf(a, b.w, acc[i].w);
        }
    }
#pragma unroll
    for (int i = 0; i < 8; ++i) {
        size_t node = node0 + nb + i;
        if (node < (size_t)N) {
            float dv = dinv[node];
            union { __half2 h2[2]; uint2 u; } p;
            p.h2[0] = __floats2half2_rn(acc[i].x * dv, acc[i].y * dv);
            p.h2[1] = __floats2half2_rn(acc[i].z * dv, acc[i].w * dv);
            *(uint2*)&xwh[node * HD + col] = p.u;
        }
    }
}

// ---------- agg1: h[n] (fp16) = relu(b1 + dinv[n]*sum_j xw[src_j]) ----------
// wave per node, half2 per lane, 8-deep independent contiguous 256B gathers

__global__ __launch_bounds__(256) void agg1(const __half2* __restrict__ xh2,
                                            const int* __restrict__ rowptr,
                                            const int* __restrict__ ep,
                                            const float* __restrict__ dinv,
                                            const float* __restrict__ b1,
                                            __half2* __restrict__ hh2) {
    int node = blockIdx.x * 4 + (threadIdx.x >> 6);
    if (node >= N) return;
    int lane = threadIdx.x & 63;
    int beg = rowptr[node], end = rowptr[node + 1];
    float ax = 0.f, ay = 0.f;
    int j = beg;
    for (; j + 8 <= end; j += 8) {
        int s0 = ep[j+0], s1 = ep[j+1], s2 = ep[j+2], s3 = ep[j+3];
        int s4 = ep[j+4], s5 = ep[j+5], s6 = ep[j+6], s7 = ep[j+7];
        __half2 v0 = xh2[(size_t)s0 * 64 + lane];
        __half2 v1 = xh2[(size_t)s1 * 64 + lane];
        __half2 v2 = xh2[(size_t)s2 * 64 + lane];
        __half2 v3 = xh2[(size_t)s3 * 64 + lane];
        __half2 v4 = xh2[(size_t)s4 * 64 + lane];
        __half2 v5 = xh2[(size_t)s5 * 64 + lane];
        __half2 v6 = xh2[(size_t)s6 * 64 + lane];
        __half2 v7 = xh2[(size_t)s7 * 64 + lane];
        float2 f;
        f = __half22float2(v0); ax += f.x; ay += f.y;
        f = __half22float2(v1); ax += f.x; ay += f.y;
        f = __half22float2(v2); ax += f.x; ay += f.y;
        f = __half22float2(v3); ax += f.x; ay += f.y;
        f = __half22float2(v4); ax += f.x; ay += f.y;
        f = __half22float2(v5); ax += f.x; ay += f.y;
        f = __half22float2(v6); ax += f.x; ay += f.y;
        f = __half22float2(v7); ax += f.x; ay += f.y;
    }
    for (; j < end; ++j) {
        float2 f = __half22float2(xh2[(size_t)ep[j] * 64 + lane]);
        ax += f.x; ay += f.y;
    }
    float dv = dinv[node];
    float2 bias = ((const float2*)b1)[lane];
    float rx = fmaxf(fmaf(dv, ax, bias.x), 0.f);
    float ry = fmaxf(fmaf(dv, ay, bias.y), 0.f);
    hh2[(size_t)node * 64 + lane] = __floats2half2_rn(rx, ry);
}

// ---------- GEMM2: xw2[N,48] (fp16) = dinv[n] * (h[N,128] @ W2[128,47]) ----------

__global__ __launch_bounds__(256) void gemm2(const __half2* __restrict__ hh2,
                                             const float* __restrict__ W2,
                                             const float* __restrict__ dinv,
                                             __half* __restrict__ xw2h) {
    __shared__ float sH[64 * 130];     // padded stride 130
    __shared__ float sW[HD * 48];      // padded to 48 cols
    int tx = threadIdx.x;
    size_t node0 = (size_t)blockIdx.x * 64;

    for (int i = tx; i < HD * 48; i += 256) {
        int k = i / 48, c = i - k * 48;
        sW[i] = (c < C) ? W2[k * C + c] : 0.f;
    }
    size_t base2 = node0 * 64;
    for (int i = tx; i < 64 * 64; i += 256) {
        size_t g = base2 + i;
        float2 f = (g < (size_t)N * 64) ? __half22float2(hh2[g]) : make_float2(0.f, 0.f);
        int row = i >> 6, c2 = (i & 63) * 2;
        sH[row * 130 + c2]     = f.x;
        sH[row * 130 + c2 + 1] = f.y;
    }
    __syncthreads();

    int c0 = (tx & 15) * 3;        // 0..45
    int nb = (tx >> 4) * 4;        // 0..60
    float acc[4][3] = {};
    for (int k = 0; k < HD; ++k) {
        float w0 = sW[k * 48 + c0];
        float w1 = sW[k * 48 + c0 + 1];
        float w2 = sW[k * 48 + c0 + 2];
#pragma unroll
        for (int i = 0; i < 4; ++i) {
            float a = sH[(nb + i) * 130 + k];
            acc[i][0] = fmaf(a, w0, acc[i][0]);
            acc[i][1] = fmaf(a, w1, acc[i][1]);
            acc[i][2] = fmaf(a, w2, acc[i][2]);
        }
    }
#pragma unroll
    for (int i = 0; i < 4; ++i) {
        size_t node = node0 + nb + i;
        if (node < (size_t)N) {
            float dv = dinv[node];
#pragma unroll
            for (int jj = 0; jj < 3; ++jj) {
                int c = c0 + jj;
                if (c < C) xw2h[node * C48 + c] = __float2half_rn(acc[i][jj] * dv);
            }
        }
    }
}

// ---------- agg2: out[n] = b2 + dinv[n] * sum_j xw2[src_j] ----------

__global__ __launch_bounds__(256) void agg2(const __half* __restrict__ xw2h,
                                            const int* __restrict__ rowptr,
                                            const int* __restrict__ ep,
                                            const float* __restrict__ dinv,
                                            const float* __restrict__ b2,
                                            float* __restrict__ out) {
    int node = blockIdx.x * 4 + (threadIdx.x >> 6);
    if (node >= N) return;
    int lane = threadIdx.x & 63;
    int beg = rowptr[node], end = rowptr[node + 1];
    float a = 0.f;
    int j = beg;
    for (; j + 8 <= end; j += 8) {
        int s0 = ep[j+0], s1 = ep[j+1], s2 = ep[j+2], s3 = ep[j+3];
        int s4 = ep[j+4], s5 = ep[j+5], s6 = ep[j+6], s7 = ep[j+7];
        __half v0 = xw2h[(size_t)s0 * C48 + lane];
        __half v1 = xw2h[(size_t)s1 * C48 + lane];
        __half v2 = xw2h[(size_t)s2 * C48 + lane];
        __half v3 = xw2h[(size_t)s3 * C48 + lane];
        __half v4 = xw2h[(size_t)s4 * C48 + lane];
        __half v5 = xw2h[(size_t)s5 * C48 + lane];
        __half v6 = xw2h[(size_t)s6 * C48 + lane];
        __half v7 = xw2h[(size_t)s7 * C48 + lane];
        a += __half2float(v0) + __half2float(v1) + __half2float(v2) + __half2float(v3)
           + __half2float(v4) + __half2float(v5) + __half2float(v6) + __half2float(v7);
    }
    for (; j < end; ++j) {
        a += __half2float(xw2h[(size_t)ep[j] * C48 + lane]);
    }
    if (lane < C) out[(size_t)node * C + lane] = fmaf(dinv[node], a, b2[lane]);
}

extern "C" void kernel_launch(void* const* d_in, const int* in_sizes, int n_in,
                              void* d_out, int out_size, void* d_ws, size_t ws_size,
                              hipStream_t stream) {
    const float* x  = (const float*)d_in[0];
    const int*   ei = (const int*)d_in[1];
    const float* W1 = (const float*)d_in[2];
    const float* b1 = (const float*)d_in[3];
    const float* W2 = (const float*)d_in[4];
    const float* b2 = (const float*)d_in[5];
    float* out = (float*)d_out;

    size_t off = 0;
    auto alloc = [&](size_t bytes) {
        void* p = (char*)d_ws + off;
        off += (bytes + 255) & ~(size_t)255;
        return p;
    };
    int*     cnt      = (int*)alloc((size_t)N * 4);
    int*     bar      = (int*)alloc(256);
    int*     rowptr   = (int*)alloc((size_t)(N + 1) * 4);
    float*   dinv     = (float*)alloc((size_t)N * 4);
    int*     ep       = (int*)alloc((size_t)EN * 4);
    int*     partials = (int*)alloc((size_t)SCAN_BLOCKS * 4);
    __half*  xwh      = (__half*)alloc((size_t)N * HD * 2);
    __half*  hh       = (__half*)alloc((size_t)N * HD * 2);
    __half*  xw2h     = (__half*)alloc((size_t)N * C48 * 2 + 64);  // +pad for lane>47 reads
    (void)ws_size;

    hipMemsetAsync(cnt, 0, (size_t)N * 4, stream);
    hipMemsetAsync(bar, 0, 256, stream);

    build_csr<<<NB_BUILD, 256, 0, stream>>>(ei, cnt, rowptr, dinv, ep, partials, bar);
    gemm1<<<(N + 63) / 64, 256, 0, stream>>>(x, W1, dinv, xwh);
    agg1<<<(N + 3) / 4, 256, 0, stream>>>((const __half2*)xwh, rowptr, ep, dinv, b1, (__half2*)hh);
    gemm2<<<(N + 63) / 64, 256, 0, stream>>>((const __half2*)hh, W2, dinv, xw2h);
    agg2<<<(N + 3) / 4, 256, 0, stream>>>(xw2h, rowptr, ep, dinv, b2, out);
}

// Round 8
// 445.618 us; speedup vs baseline: 2.0611x; 2.0611x over previous
//
#include <hip/hip_runtime.h>
#include <hip/hip_bf16.h>
#include <hip/hip_fp16.h>

// GCN 2-layer inference, N=100000, E=1600000, F_IN=100, H=128, C=47.
// R8: revert to the proven multi-launch pipeline (R3 structure, best=445us).
// Grid-barrier fusion (R7) and single-block scan (R6) both parked the machine
// for >250us; small latency-bound kernels + ~5us launch gaps win. Kept deltas:
// int4 4-edge/thread count+scatter (atomic-free scatter via precomputed slot),
// dinv folded into gemm outputs (agg = pure sum), gemm2 BEFORE agg2 (96B
// gathers), 2-launch scan (pass2 folded into pass3, redundant 49-int scan).

constexpr int N    = 100000;
constexpr int E    = 1600000;
constexpr int FIN  = 100;
constexpr int HD   = 128;
constexpr int C    = 47;
constexpr int C48  = 48;
constexpr int EN   = E + N;          // edges + self loops
constexpr int SCAN_CHUNK = 2048;     // 256 threads * 8
constexpr int NB_SCAN = (N + SCAN_CHUNK - 1) / SCAN_CHUNK;  // 49

// ---------- count: deg + per-edge slot (4 edges/thread, int4) ----------

__global__ __launch_bounds__(256) void count_pos(const int* __restrict__ dst,
                                                 int* __restrict__ cnt,
                                                 int* __restrict__ epos) {
    int t = blockIdx.x * 256 + threadIdx.x;
    int e0 = t * 4;
    if (e0 + 4 <= E) {
        int4 d = *(const int4*)(dst + e0);
        int p0 = atomicAdd(&cnt[d.x], 1);
        int p1 = atomicAdd(&cnt[d.y], 1);
        int p2 = atomicAdd(&cnt[d.z], 1);
        int p3 = atomicAdd(&cnt[d.w], 1);
        *(int4*)(epos + e0) = make_int4(p0, p1, p2, p3);
    } else {
        for (int e = e0; e < E; ++e) epos[e] = atomicAdd(&cnt[dst[e]], 1);
    }
}

// ---------- scan pass 1: per-block partial sums of (deg+1) ----------

__global__ __launch_bounds__(256) void scan_pass1(const int* __restrict__ cnt,
                                                  int* __restrict__ partials) {
    int t = threadIdx.x, b = blockIdx.x;
    int base = b * SCAN_CHUNK + t * 8;
    int s = 0;
#pragma unroll
    for (int i = 0; i < 8; ++i) {
        int idx = base + i;
        if (idx < N) s += cnt[idx] + 1;   // +1 self loop
    }
    __shared__ int sm[256];
    sm[t] = s;
    __syncthreads();
    for (int off = 128; off > 0; off >>= 1) {
        if (t < off) sm[t] += sm[t + off];
        __syncthreads();
    }
    if (t == 0) partials[b] = sm[0];
}

// ---------- scan pass 2: rowptr + dinv + self-loop slots ----------
// each block redundantly scans the 49 partials (cheap) -> no serial launch

__global__ __launch_bounds__(256) void scan_pass2(const int* __restrict__ cnt,
                                                  const int* __restrict__ partials,
                                                  int* __restrict__ rowptr,
                                                  float* __restrict__ dinv,
                                                  int* __restrict__ ep) {
    int t = threadIdx.x, b = blockIdx.x;
    __shared__ int spre;
    if (t == 0) {
        int run = 0;
        for (int i = 0; i < b; ++i) run += partials[i];
        spre = run;
    }
    int base = b * SCAN_CHUNK + t * 8;
    int v[8];
    int s = 0;
#pragma unroll
    for (int i = 0; i < 8; ++i) {
        int idx = base + i;
        v[i] = (idx < N) ? cnt[idx] + 1 : 0;   // deg incl self loop
        s += v[i];
    }
    __shared__ int sm[256];
    sm[t] = s;
    __syncthreads();
    for (int off = 1; off < 256; off <<= 1) {
        int tv = (t >= off) ? sm[t - off] : 0;
        __syncthreads();
        sm[t] += tv;
        __syncthreads();
    }
    int excl = sm[t] - s + spre;
#pragma unroll
    for (int i = 0; i < 8; ++i) {
        int idx = base + i;
        if (idx < N) {
            rowptr[idx] = excl;
            ep[excl] = idx;                   // self loop at slot 0
            dinv[idx] = rsqrtf((float)v[i]);
            excl += v[i];
        }
    }
    if (b == 0 && t == 0) rowptr[N] = EN;
}

// ---------- scatter: 4 edges/thread, no atomics ----------

__global__ __launch_bounds__(256) void scatter_edges(const int* __restrict__ ei,
                                                     const int* __restrict__ rowptr,
                                                     const int* __restrict__ epos,
                                                     int* __restrict__ ep) {
    int t = blockIdx.x * 256 + threadIdx.x;
    int e0 = t * 4;
    if (e0 + 4 <= E) {
        int4 s = *(const int4*)(ei + e0);
        int4 d = *(const int4*)(ei + E + e0);
        int4 p = *(const int4*)(epos + e0);
        int r0 = rowptr[d.x], r1 = rowptr[d.y], r2 = rowptr[d.z], r3 = rowptr[d.w];
        ep[r0 + 1 + p.x] = s.x;
        ep[r1 + 1 + p.y] = s.y;
        ep[r2 + 1 + p.z] = s.z;
        ep[r3 + 1 + p.w] = s.w;
    } else {
        for (int e = e0; e < E; ++e)
            ep[rowptr[ei[E + e]] + 1 + epos[e]] = ei[e];
    }
}

// ---------- GEMM1: xw[N,128] (fp16) = dinv[n] * (x[N,100] @ W1) ----------

__global__ __launch_bounds__(256) void gemm1(const float* __restrict__ x,
                                             const float* __restrict__ W1,
                                             const float* __restrict__ dinv,
                                             __half* __restrict__ xwh) {
    __shared__ float sW[FIN * HD];     // 51.2 KB
    __shared__ float sX[64 * FIN];     // 25.6 KB
    int tx = threadIdx.x;
    size_t node0 = (size_t)blockIdx.x * 64;

    const float4* W4 = (const float4*)W1;
    for (int i = tx; i < FIN * HD / 4; i += 256) ((float4*)sW)[i] = W4[i];
    size_t base4 = node0 * FIN / 4;          // node0*100 divisible by 4
    const float4* x4 = (const float4*)x;
    for (int i = tx; i < 64 * FIN / 4; i += 256) {
        size_t g = base4 + i;
        ((float4*)sX)[i] = (g < (size_t)N * FIN / 4) ? x4[g]
                                                     : make_float4(0.f, 0.f, 0.f, 0.f);
    }
    __syncthreads();

    int col = (tx & 31) * 4;        // 0..124
    int nb  = (tx >> 5) * 8;        // 0..56
    float4 acc[8];
#pragma unroll
    for (int i = 0; i < 8; ++i) acc[i] = make_float4(0.f, 0.f, 0.f, 0.f);

    for (int k = 0; k < FIN; ++k) {
        float4 b = *(const float4*)&sW[k * HD + col];
#pragma unroll
        for (int i = 0; i < 8; ++i) {
            float a = sX[(nb + i) * FIN + k];
            acc[i].x = fmaf(a, b.x, acc[i].x);
            acc[i].y = fmaf(a, b.y, acc[i].y);
            acc[i].z = fmaf(a, b.z, acc[i].z);
            acc[i].w = fmaf(a, b.w, acc[i].w);
        }
    }
#pragma unroll
    for (int i = 0; i < 8; ++i) {
        size_t node = node0 + nb + i;
        if (node < (size_t)N) {
            float dv = dinv[node];
            union { __half2 h2[2]; uint2 u; } p;
            p.h2[0] = __floats2half2_rn(acc[i].x * dv, acc[i].y * dv);
            p.h2[1] = __floats2half2_rn(acc[i].z * dv, acc[i].w * dv);
            *(uint2*)&xwh[node * HD + col] = p.u;
        }
    }
}

// ---------- agg1: h[n] (fp16) = relu(b1 + dinv[n]*sum_j xw[src_j]) ----------
// wave per node, half2 per lane, 8-deep independent contiguous 256B gathers

__global__ __launch_bounds__(256) void agg1(const __half2* __restrict__ xh2,
                                            const int* __restrict__ rowptr,
                                            const int* __restrict__ ep,
                                            const float* __restrict__ dinv,
                                            const float* __restrict__ b1,
                                            __half2* __restrict__ hh2) {
    int node = blockIdx.x * 4 + (threadIdx.x >> 6);
    if (node >= N) return;
    int lane = threadIdx.x & 63;
    int beg = rowptr[node], end = rowptr[node + 1];
    float ax = 0.f, ay = 0.f;
    int j = beg;
    for (; j + 8 <= end; j += 8) {
        int s0 = ep[j+0], s1 = ep[j+1], s2 = ep[j+2], s3 = ep[j+3];
        int s4 = ep[j+4], s5 = ep[j+5], s6 = ep[j+6], s7 = ep[j+7];
        __half2 v0 = xh2[(size_t)s0 * 64 + lane];
        __half2 v1 = xh2[(size_t)s1 * 64 + lane];
        __half2 v2 = xh2[(size_t)s2 * 64 + lane];
        __half2 v3 = xh2[(size_t)s3 * 64 + lane];
        __half2 v4 = xh2[(size_t)s4 * 64 + lane];
        __half2 v5 = xh2[(size_t)s5 * 64 + lane];
        __half2 v6 = xh2[(size_t)s6 * 64 + lane];
        __half2 v7 = xh2[(size_t)s7 * 64 + lane];
        float2 f;
        f = __half22float2(v0); ax += f.x; ay += f.y;
        f = __half22float2(v1); ax += f.x; ay += f.y;
        f = __half22float2(v2); ax += f.x; ay += f.y;
        f = __half22float2(v3); ax += f.x; ay += f.y;
        f = __half22float2(v4); ax += f.x; ay += f.y;
        f = __half22float2(v5); ax += f.x; ay += f.y;
        f = __half22float2(v6); ax += f.x; ay += f.y;
        f = __half22float2(v7); ax += f.x; ay += f.y;
    }
    for (; j < end; ++j) {
        float2 f = __half22float2(xh2[(size_t)ep[j] * 64 + lane]);
        ax += f.x; ay += f.y;
    }
    float dv = dinv[node];
    float2 bias = ((const float2*)b1)[lane];
    float rx = fmaxf(fmaf(dv, ax, bias.x), 0.f);
    float ry = fmaxf(fmaf(dv, ay, bias.y), 0.f);
    hh2[(size_t)node * 64 + lane] = __floats2half2_rn(rx, ry);
}

// ---------- GEMM2: xw2[N,48] (fp16) = dinv[n] * (h[N,128] @ W2[128,47]) ----------

__global__ __launch_bounds__(256) void gemm2(const __half2* __restrict__ hh2,
                                             const float* __restrict__ W2,
                                             const float* __restrict__ dinv,
                                             __half* __restrict__ xw2h) {
    __shared__ float sH[64 * 130];     // padded stride 130
    __shared__ float sW[HD * 48];      // padded to 48 cols
    int tx = threadIdx.x;
    size_t node0 = (size_t)blockIdx.x * 64;

    for (int i = tx; i < HD * 48; i += 256) {
        int k = i / 48, c = i - k * 48;
        sW[i] = (c < C) ? W2[k * C + c] : 0.f;
    }
    size_t base2 = node0 * 64;
    for (int i = tx; i < 64 * 64; i += 256) {
        size_t g = base2 + i;
        float2 f = (g < (size_t)N * 64) ? __half22float2(hh2[g]) : make_float2(0.f, 0.f);
        int row = i >> 6, c2 = (i & 63) * 2;
        sH[row * 130 + c2]     = f.x;
        sH[row * 130 + c2 + 1] = f.y;
    }
    __syncthreads();

    int c0 = (tx & 15) * 3;        // 0..45
    int nb = (tx >> 4) * 4;        // 0..60
    float acc[4][3] = {};
    for (int k = 0; k < HD; ++k) {
        float w0 = sW[k * 48 + c0];
        float w1 = sW[k * 48 + c0 + 1];
        float w2 = sW[k * 48 + c0 + 2];
#pragma unroll
        for (int i = 0; i < 4; ++i) {
            float a = sH[(nb + i) * 130 + k];
            acc[i][0] = fmaf(a, w0, acc[i][0]);
            acc[i][1] = fmaf(a, w1, acc[i][1]);
            acc[i][2] = fmaf(a, w2, acc[i][2]);
        }
    }
#pragma unroll
    for (int i = 0; i < 4; ++i) {
        size_t node = node0 + nb + i;
        if (node < (size_t)N) {
            float dv = dinv[node];
#pragma unroll
            for (int jj = 0; jj < 3; ++jj) {
                int c = c0 + jj;
                if (c < C) xw2h[node * C48 + c] = __float2half_rn(acc[i][jj] * dv);
            }
        }
    }
}

// ---------- agg2: out[n] = b2 + dinv[n] * sum_j xw2[src_j] ----------

__global__ __launch_bounds__(256) void agg2(const __half* __restrict__ xw2h,
                                            const int* __restrict__ rowptr,
                                            const int* __restrict__ ep,
                                            const float* __restrict__ dinv,
                                            const float* __restrict__ b2,
                                            float* __restrict__ out) {
    int node = blockIdx.x * 4 + (threadIdx.x >> 6);
    if (node >= N) return;
    int lane = threadIdx.x & 63;
    int beg = rowptr[node], end = rowptr[node + 1];
    float a = 0.f;
    int j = beg;
    for (; j + 8 <= end; j += 8) {
        int s0 = ep[j+0], s1 = ep[j+1], s2 = ep[j+2], s3 = ep[j+3];
        int s4 = ep[j+4], s5 = ep[j+5], s6 = ep[j+6], s7 = ep[j+7];
        __half v0 = xw2h[(size_t)s0 * C48 + lane];
        __half v1 = xw2h[(size_t)s1 * C48 + lane];
        __half v2 = xw2h[(size_t)s2 * C48 + lane];
        __half v3 = xw2h[(size_t)s3 * C48 + lane];
        __half v4 = xw2h[(size_t)s4 * C48 + lane];
        __half v5 = xw2h[(size_t)s5 * C48 + lane];
        __half v6 = xw2h[(size_t)s6 * C48 + lane];
        __half v7 = xw2h[(size_t)s7 * C48 + lane];
        a += __half2float(v0) + __half2float(v1) + __half2float(v2) + __half2float(v3)
           + __half2float(v4) + __half2float(v5) + __half2float(v6) + __half2float(v7);
    }
    for (; j < end; ++j) {
        a += __half2float(xw2h[(size_t)ep[j] * C48 + lane]);
    }
    if (lane < C) out[(size_t)node * C + lane] = fmaf(dinv[node], a, b2[lane]);
}

extern "C" void kernel_launch(void* const* d_in, const int* in_sizes, int n_in,
                              void* d_out, int out_size, void* d_ws, size_t ws_size,
                              hipStream_t stream) {
    const float* x  = (const float*)d_in[0];
    const int*   ei = (const int*)d_in[1];
    const float* W1 = (const float*)d_in[2];
    const float* b1 = (const float*)d_in[3];
    const float* W2 = (const float*)d_in[4];
    const float* b2 = (const float*)d_in[5];
    float* out = (float*)d_out;

    size_t off = 0;
    auto alloc = [&](size_t bytes) {
        void* p = (char*)d_ws + off;
        off += (bytes + 255) & ~(size_t)255;
        return p;
    };
    int*     cnt      = (int*)alloc((size_t)N * 4);
    int*     rowptr   = (int*)alloc((size_t)(N + 1) * 4);
    int*     epos     = (int*)alloc((size_t)E * 4);
    int*     partials = (int*)alloc((size_t)NB_SCAN * 4);
    float*   dinv     = (float*)alloc((size_t)N * 4);
    int*     ep       = (int*)alloc((size_t)EN * 4);
    __half*  xwh      = (__half*)alloc((size_t)N * HD * 2);
    __half*  hh       = (__half*)alloc((size_t)N * HD * 2);
    __half*  xw2h     = (__half*)alloc((size_t)N * C48 * 2 + 64);  // +pad for lane>47 reads
    (void)ws_size;

    int gE4 = (E / 4 + 255) / 256;   // 4 edges per thread

    hipMemsetAsync(cnt, 0, (size_t)N * 4, stream);
    count_pos<<<gE4, 256, 0, stream>>>(ei + E, cnt, epos);
    scan_pass1<<<NB_SCAN, 256, 0, stream>>>(cnt, partials);
    scan_pass2<<<NB_SCAN, 256, 0, stream>>>(cnt, partials, rowptr, dinv, ep);
    scatter_edges<<<gE4, 256, 0, stream>>>(ei, rowptr, epos, ep);
    gemm1<<<(N + 63) / 64, 256, 0, stream>>>(x, W1, dinv, xwh);
    agg1<<<(N + 3) / 4, 256, 0, stream>>>((const __half2*)xwh, rowptr, ep, dinv, b1, (__half2*)hh);
    gemm2<<<(N + 63) / 64, 256, 0, stream>>>((const __half2*)hh, W2, dinv, xw2h);
    agg2<<<(N + 3) / 4, 256, 0, stream>>>(xw2h, rowptr, ep, dinv, b2, out);
}